// Round 1
// baseline (122.772 us; speedup 1.0000x reference)
//
#include <hip/hip_runtime.h>
#include <hip/hip_bf16.h>
#include <math.h>

typedef __attribute__((ext_vector_type(8))) __bf16 bf16x8;
typedef __attribute__((ext_vector_type(4))) __bf16 bf16x4;
typedef __attribute__((ext_vector_type(4))) float f32x4;

#define EE 1024
#define HH 16
#define DD 64
#define BB 8
#define TT 64
#define NSPLIT 9

__device__ __forceinline__ f32x4 mfma16(bf16x8 a, bf16x8 b, f32x4 c) {
    return __builtin_amdgcn_mfma_f32_16x16x32_bf16(a, b, c, 0, 0, 0);
}

// ---- RoPE tables: angle depends only on (head, pair) because of the source bug ----
__global__ void k_table(const int* __restrict__ sp_ptr, float* __restrict__ cs, float* __restrict__ sn) {
    int i = threadIdx.x;          // 0..511 = h*32 + p
    int h = i >> 5, p = i & 31;
    int sp = sp_ptr[0];
    double inv = 1.0 / pow(10000.0, (double)p / 32.0);
    double ang = (double)(sp + h) * inv;
    cs[i] = (float)cos(ang);
    sn[i] = (float)sin(ang);
}

// ---- convert + transpose weights to bf16: WT[w][n][k] ----
__global__ __launch_bounds__(256) void k_convw(const float* __restrict__ Wq, const float* __restrict__ Wk,
                                               const float* __restrict__ Wv, const float* __restrict__ Wo,
                                               __bf16* __restrict__ WT) {
    __shared__ float tile[64][68];
    int gid = blockIdx.x;
    int w = gid >> 8, tl = gid & 255;
    int k0 = (tl >> 4) * 64, n0 = (tl & 15) * 64;
    const float* W = (w == 0) ? Wq : (w == 1) ? Wk : (w == 2) ? Wv : Wo;
    int tid = threadIdx.x;
#pragma unroll
    for (int p = 0; p < 4; ++p) {
        int idx = p * 256 + tid;
        int r = idx >> 4, c4 = (idx & 15) * 4;
        float4 f = *(const float4*)&W[(size_t)(k0 + r) * EE + n0 + c4];
        *(float4*)&tile[r][c4] = f;
    }
    __syncthreads();
    __bf16* out = WT + (size_t)w * EE * EE;
#pragma unroll
    for (int p = 0; p < 2; ++p) {
        int q = p * 256 + tid;
        int r = q >> 3, c8 = (q & 7) * 8;
        bf16x8 v;
#pragma unroll
        for (int j = 0; j < 8; ++j) v[j] = (__bf16)tile[c8 + j][r];
        *(bf16x8*)&out[(size_t)(n0 + r) * EE + k0 + c8] = v;
    }
}

// ---- convert x to bf16 ----
__global__ __launch_bounds__(256) void k_convx(const float* __restrict__ x, __bf16* __restrict__ xb) {
    int i = (blockIdx.x * 256 + threadIdx.x) * 8;
    float4 a = *(const float4*)&x[i];
    float4 b = *(const float4*)&x[i + 4];
    bf16x8 v;
    v[0] = (__bf16)a.x; v[1] = (__bf16)a.y; v[2] = (__bf16)a.z; v[3] = (__bf16)a.w;
    v[4] = (__bf16)b.x; v[5] = (__bf16)b.y; v[6] = (__bf16)b.z; v[7] = (__bf16)b.w;
    *(bf16x8*)&xb[i] = v;
}

// ---- fused QKV projection + RoPE, outputs (B,H,T,D) bf16 ----
__global__ __launch_bounds__(256) void k_qkv(const __bf16* __restrict__ xb, const __bf16* __restrict__ WT,
                                             const float* __restrict__ cs, const float* __restrict__ sn,
                                             __bf16* __restrict__ qws, __bf16* __restrict__ knew,
                                             __bf16* __restrict__ vnew) {
    __shared__ __bf16 a_lds[64][72];
    __shared__ __bf16 b_lds[64][72];
    int bm = blockIdx.x / 48, bn = blockIdx.x % 48;
    int wsel = bn >> 4;              // 0=q, 1=k, 2=v
    int n0 = (bn & 15) * 64;
    int m0 = bm * 64;
    const __bf16* Wt = WT + (size_t)wsel * EE * EE;
    int tid = threadIdx.x;
    int wv = tid >> 6, lane = tid & 63;
    int l16 = lane & 15, lhi = lane >> 4;

    f32x4 acc[4];
#pragma unroll
    for (int f = 0; f < 4; ++f) acc[f] = (f32x4){0.f, 0.f, 0.f, 0.f};

    for (int kt = 0; kt < 16; ++kt) {
        __syncthreads();
#pragma unroll
        for (int p = 0; p < 2; ++p) {
            int idx = p * 256 + tid;
            int r = idx >> 3, c8 = (idx & 7) * 8;
            *(bf16x8*)&a_lds[r][c8] = *(const bf16x8*)&xb[(size_t)(m0 + r) * EE + kt * 64 + c8];
            *(bf16x8*)&b_lds[r][c8] = *(const bf16x8*)&Wt[(size_t)(n0 + r) * EE + kt * 64 + c8];
        }
        __syncthreads();
        bf16x8 a0 = *(bf16x8*)&a_lds[wv * 16 + l16][lhi * 8];
        bf16x8 a1 = *(bf16x8*)&a_lds[wv * 16 + l16][32 + lhi * 8];
#pragma unroll
        for (int f = 0; f < 4; ++f) {
            bf16x8 b0 = *(bf16x8*)&b_lds[f * 16 + l16][lhi * 8];
            bf16x8 b1 = *(bf16x8*)&b_lds[f * 16 + l16][32 + lhi * 8];
            acc[f] = mfma16(a0, b0, acc[f]);
            acc[f] = mfma16(a1, b1, acc[f]);
        }
    }
    __bf16* dst = (wsel == 0) ? qws : (wsel == 1) ? knew : vnew;
#pragma unroll
    for (int f = 0; f < 4; ++f) {
#pragma unroll
        for (int r = 0; r < 4; ++r) {
            float v = acc[f][r];
            int row = m0 + wv * 16 + lhi * 4 + r;
            int ng = n0 + f * 16 + l16;
            int h = ng >> 6, d = ng & 63;
            float o = v;
            if (wsel < 2) {
                float other = __shfl_xor(v, 1);   // partner column (d^1) same row
                int pp = d >> 1;
                float c = cs[h * 32 + pp], s = sn[h * 32 + pp];
                o = ((d & 1) == 0) ? (v * c - other * s) : (other * s + v * c);
            }
            int b = row >> 6, t = row & 63;
            dst[((size_t)((b * HH + h) * TT + t)) * DD + d] = (__bf16)o;
        }
    }
}

// ---- flash-decoding attention: grid = B*H*NSPLIT, block = 256 (4 waves) ----
__global__ __launch_bounds__(256) void k_attn(const __bf16* __restrict__ qws, const __bf16* __restrict__ knew,
                                              const __bf16* __restrict__ vnew,
                                              const float* __restrict__ ck, const float* __restrict__ cv,
                                              float* __restrict__ Opart, float* __restrict__ mpart,
                                              float* __restrict__ lpart) {
    __shared__ __bf16 k_lds[64][72];    // [s][d]
    __shared__ __bf16 vT_lds[64][72];   // [d][s]
    __shared__ __bf16 p_lds[64][72];    // [t][s]
    int bh = blockIdx.x / NSPLIT, split = blockIdx.x % NSPLIT;
    int b = bh >> 4, h = bh & 15;
    int tid = threadIdx.x, wv = tid >> 6, lane = tid & 63;
    int l16 = lane & 15, lhi = lane >> 4;

    // Q fragments (A operand), rows t = wv*16 + l16
    bf16x8 qf0, qf1;
    {
        const __bf16* qp = qws + ((size_t)bh * TT + (wv * 16 + l16)) * DD;
        qf0 = *(const bf16x8*)&qp[lhi * 8];
        qf1 = *(const bf16x8*)&qp[32 + lhi * 8];
    }
    f32x4 acc[4];
#pragma unroll
    for (int f = 0; f < 4; ++f) acc[f] = (f32x4){0.f, 0.f, 0.f, 0.f};
    float m[4], l[4];
#pragma unroll
    for (int r = 0; r < 4; ++r) { m[r] = -1e30f; l[r] = 0.f; }

    int ntiles = (split < 8) ? 8 : 1;
    for (int it = 0; it < ntiles; ++it) {
        __syncthreads();
        if (split < 8) {
            int s0 = split * 512 + it * 64;
#pragma unroll
            for (int p = 0; p < 4; ++p) {
                int idx = p * 256 + tid;
                int r = idx >> 4, c4 = (idx & 15) * 4;
                size_t base = (((size_t)b * 8192 + s0 + r) * HH + h) * DD + c4;
                float4 kf = *(const float4*)&ck[base];
                float4 vf = *(const float4*)&cv[base];
                bf16x4 k4 = { (__bf16)kf.x, (__bf16)kf.y, (__bf16)kf.z, (__bf16)kf.w };
                *(bf16x4*)&k_lds[r][c4] = k4;
                vT_lds[c4 + 0][r] = (__bf16)vf.x;
                vT_lds[c4 + 1][r] = (__bf16)vf.y;
                vT_lds[c4 + 2][r] = (__bf16)vf.z;
                vT_lds[c4 + 3][r] = (__bf16)vf.w;
            }
        } else {
#pragma unroll
            for (int p = 0; p < 2; ++p) {
                int idx = p * 256 + tid;
                int r = idx >> 3, c8 = (idx & 7) * 8;
                *(bf16x8*)&k_lds[r][c8] = *(const bf16x8*)&knew[((size_t)bh * TT + r) * DD + c8];
                bf16x8 vf = *(const bf16x8*)&vnew[((size_t)bh * TT + r) * DD + c8];
#pragma unroll
                for (int j = 0; j < 8; ++j) vT_lds[c8 + j][r] = vf[j];
            }
        }
        __syncthreads();

        // scores = Q * K^T  (M=t, N=s, K=d)
        f32x4 sf[4];
#pragma unroll
        for (int f = 0; f < 4; ++f) {
            f32x4 z = (f32x4){0.f, 0.f, 0.f, 0.f};
            bf16x8 b0 = *(bf16x8*)&k_lds[f * 16 + l16][lhi * 8];
            bf16x8 b1 = *(bf16x8*)&k_lds[f * 16 + l16][32 + lhi * 8];
            z = mfma16(qf0, b0, z);
            z = mfma16(qf1, b1, z);
            sf[f] = z;
        }
        // scale + causal mask (only the 'new keys' split needs masking)
#pragma unroll
        for (int f = 0; f < 4; ++f) {
#pragma unroll
            for (int r = 0; r < 4; ++r) {
                float sv = sf[f][r] * 0.125f;
                if (split == 8) {
                    int t_row = wv * 16 + lhi * 4 + r;
                    int s_loc = f * 16 + l16;
                    if (s_loc > t_row) sv = -1e30f;
                }
                sf[f][r] = sv;
            }
        }
        // row max across the 16-lane col group
        float mt[4];
#pragma unroll
        for (int r = 0; r < 4; ++r)
            mt[r] = fmaxf(fmaxf(sf[0][r], sf[1][r]), fmaxf(sf[2][r], sf[3][r]));
#pragma unroll
        for (int off = 1; off < 16; off <<= 1) {
#pragma unroll
            for (int r = 0; r < 4; ++r) mt[r] = fmaxf(mt[r], __shfl_xor(mt[r], off));
        }
        float fac[4];
#pragma unroll
        for (int r = 0; r < 4; ++r) {
            float mn = fmaxf(m[r], mt[r]);
            fac[r] = __expf(m[r] - mn);
            m[r] = mn;
        }
        float ladd[4] = {0.f, 0.f, 0.f, 0.f};
#pragma unroll
        for (int f = 0; f < 4; ++f) {
#pragma unroll
            for (int r = 0; r < 4; ++r) {
                float pv = __expf(sf[f][r] - m[r]);
                sf[f][r] = pv;
                ladd[r] += pv;
            }
        }
#pragma unroll
        for (int off = 1; off < 16; off <<= 1) {
#pragma unroll
            for (int r = 0; r < 4; ++r) ladd[r] += __shfl_xor(ladd[r], off);
        }
#pragma unroll
        for (int r = 0; r < 4; ++r) l[r] = l[r] * fac[r] + ladd[r];
#pragma unroll
        for (int f = 0; f < 4; ++f)
#pragma unroll
            for (int r = 0; r < 4; ++r) acc[f][r] *= fac[r];
        // P -> LDS (per-wave rows), then PV
#pragma unroll
        for (int f = 0; f < 4; ++f)
#pragma unroll
            for (int r = 0; r < 4; ++r)
                p_lds[wv * 16 + lhi * 4 + r][f * 16 + l16] = (__bf16)sf[f][r];
        __syncthreads();
        bf16x8 pa0 = *(bf16x8*)&p_lds[wv * 16 + l16][lhi * 8];
        bf16x8 pa1 = *(bf16x8*)&p_lds[wv * 16 + l16][32 + lhi * 8];
#pragma unroll
        for (int f = 0; f < 4; ++f) {
            bf16x8 v0 = *(bf16x8*)&vT_lds[f * 16 + l16][lhi * 8];
            bf16x8 v1 = *(bf16x8*)&vT_lds[f * 16 + l16][32 + lhi * 8];
            acc[f] = mfma16(pa0, v0, acc[f]);
            acc[f] = mfma16(pa1, v1, acc[f]);
        }
    }
    // store partials
#pragma unroll
    for (int f = 0; f < 4; ++f)
#pragma unroll
        for (int r = 0; r < 4; ++r) {
            int t = wv * 16 + lhi * 4 + r;
            int d = f * 16 + l16;
            Opart[(((size_t)split * 128 + bh) * TT + t) * DD + d] = acc[f][r];
        }
    if (l16 == 0) {
#pragma unroll
        for (int r = 0; r < 4; ++r) {
            int t = wv * 16 + lhi * 4 + r;
            mpart[((size_t)split * 128 + bh) * TT + t] = m[r];
            lpart[((size_t)split * 128 + bh) * TT + t] = l[r];
        }
    }
}

// ---- combine split partials -> ctx bf16 (row-major tokens x E) ----
__global__ __launch_bounds__(256) void k_combine(const float* __restrict__ Opart, const float* __restrict__ mpart,
                                                 const float* __restrict__ lpart, __bf16* __restrict__ ctxb) {
    int idx = blockIdx.x * 256 + threadIdx.x;   // B*H*T*D = 524288
    int d = idx & 63, t = (idx >> 6) & 63, bh = idx >> 12;
    float ms[NSPLIT], ls[NSPLIT];
    float mg = -1e30f;
#pragma unroll
    for (int s = 0; s < NSPLIT; ++s) {
        ms[s] = mpart[((size_t)s * 128 + bh) * TT + t];
        ls[s] = lpart[((size_t)s * 128 + bh) * TT + t];
        mg = fmaxf(mg, ms[s]);
    }
    float den = 0.f, num = 0.f;
#pragma unroll
    for (int s = 0; s < NSPLIT; ++s) {
        float w = __expf(ms[s] - mg);
        den += ls[s] * w;
        num += Opart[(((size_t)s * 128 + bh) * TT + t) * DD + d] * w;
    }
    float ctx = num / den;
    int b = bh >> 4, hh = bh & 15;
    ctxb[(size_t)(b * TT + t) * EE + hh * DD + d] = (__bf16)ctx;
}

// ---- output projection: out = ctx @ Wo ----
__global__ __launch_bounds__(256) void k_oproj(const __bf16* __restrict__ ctxb, const __bf16* __restrict__ WoT,
                                               float* __restrict__ out) {
    __shared__ __bf16 a_lds[64][72];
    __shared__ __bf16 b_lds[64][72];
    int bm = blockIdx.x >> 4, bn = blockIdx.x & 15;
    int n0 = bn * 64, m0 = bm * 64;
    int tid = threadIdx.x;
    int wv = tid >> 6, lane = tid & 63;
    int l16 = lane & 15, lhi = lane >> 4;
    f32x4 acc[4];
#pragma unroll
    for (int f = 0; f < 4; ++f) acc[f] = (f32x4){0.f, 0.f, 0.f, 0.f};

    for (int kt = 0; kt < 16; ++kt) {
        __syncthreads();
#pragma unroll
        for (int p = 0; p < 2; ++p) {
            int idx = p * 256 + tid;
            int r = idx >> 3, c8 = (idx & 7) * 8;
            *(bf16x8*)&a_lds[r][c8] = *(const bf16x8*)&ctxb[(size_t)(m0 + r) * EE + kt * 64 + c8];
            *(bf16x8*)&b_lds[r][c8] = *(const bf16x8*)&WoT[(size_t)(n0 + r) * EE + kt * 64 + c8];
        }
        __syncthreads();
        bf16x8 a0 = *(bf16x8*)&a_lds[wv * 16 + l16][lhi * 8];
        bf16x8 a1 = *(bf16x8*)&a_lds[wv * 16 + l16][32 + lhi * 8];
#pragma unroll
        for (int f = 0; f < 4; ++f) {
            bf16x8 b0 = *(bf16x8*)&b_lds[f * 16 + l16][lhi * 8];
            bf16x8 b1 = *(bf16x8*)&b_lds[f * 16 + l16][32 + lhi * 8];
            acc[f] = mfma16(a0, b0, acc[f]);
            acc[f] = mfma16(a1, b1, acc[f]);
        }
    }
#pragma unroll
    for (int f = 0; f < 4; ++f)
#pragma unroll
        for (int r = 0; r < 4; ++r) {
            int row = m0 + wv * 16 + lhi * 4 + r;
            out[(size_t)row * EE + n0 + f * 16 + l16] = acc[f][r];
        }
}

extern "C" void kernel_launch(void* const* d_in, const int* in_sizes, int n_in,
                              void* d_out, int out_size, void* d_ws, size_t ws_size,
                              hipStream_t stream) {
    const float* x  = (const float*)d_in[0];
    const float* ck = (const float*)d_in[1];
    const float* cv = (const float*)d_in[2];
    const float* Wq = (const float*)d_in[3];
    const float* Wk = (const float*)d_in[4];
    const float* Wv = (const float*)d_in[5];
    const float* Wo = (const float*)d_in[6];
    const int* sp   = (const int*)d_in[7];
    float* out = (float*)d_out;

    char* p = (char*)d_ws;
    float* cs = (float*)p;              p += 2048;
    float* sn = (float*)p;              p += 2048;
    __bf16* xb = (__bf16*)p;            p += (size_t)512 * 1024 * 2;
    __bf16* WT = (__bf16*)p;            p += (size_t)4 * 1024 * 1024 * 2;
    __bf16* qws = (__bf16*)p;           p += (size_t)524288 * 2;
    __bf16* knew = (__bf16*)p;          p += (size_t)524288 * 2;
    __bf16* vnew = (__bf16*)p;          p += (size_t)524288 * 2;
    float* Opart = (float*)p;           p += (size_t)NSPLIT * 128 * 64 * 64 * 4;
    float* mpart = (float*)p;           p += (size_t)NSPLIT * 8192 * 4;
    float* lpart = (float*)p;           p += (size_t)NSPLIT * 8192 * 4;
    __bf16* ctxb = (__bf16*)p;          p += (size_t)524288 * 2;

    k_table<<<1, 512, 0, stream>>>(sp, cs, sn);
    k_convw<<<1024, 256, 0, stream>>>(Wq, Wk, Wv, Wo, WT);
    k_convx<<<256, 256, 0, stream>>>(x, xb);
    k_qkv<<<384, 256, 0, stream>>>(xb, WT, cs, sn, qws, knew, vnew);
    k_attn<<<BB * HH * NSPLIT, 256, 0, stream>>>(qws, knew, vnew, ck, cv, Opart, mpart, lpart);
    k_combine<<<2048, 256, 0, stream>>>(Opart, mpart, lpart, ctxb);
    k_oproj<<<128, 256, 0, stream>>>(ctxb, WT + (size_t)3 * 1024 * 1024, out);
}

// Round 2
// 101.624 us; speedup vs baseline: 1.2081x; 1.2081x over previous
//
#include <hip/hip_runtime.h>
#include <hip/hip_bf16.h>
#include <math.h>

typedef __attribute__((ext_vector_type(8))) __bf16 bf16x8;
typedef __attribute__((ext_vector_type(4))) __bf16 bf16x4;
typedef __attribute__((ext_vector_type(4))) float f32x4;

#define EE 1024
#define HH 16
#define DD 64
#define BB 8
#define TT 64
#define NSPLIT 8

__device__ __forceinline__ f32x4 mfma16(bf16x8 a, bf16x8 b, f32x4 c) {
    return __builtin_amdgcn_mfma_f32_16x16x32_bf16(a, b, c, 0, 0, 0);
}

// ---- fused prep: weight transpose+convert, x convert, RoPE tables ----
__global__ __launch_bounds__(256) void k_prep(const float* __restrict__ Wq, const float* __restrict__ Wk,
                                              const float* __restrict__ Wv, const float* __restrict__ Wo,
                                              const float* __restrict__ x, const int* __restrict__ sp_ptr,
                                              __bf16* __restrict__ WT, __bf16* __restrict__ xb,
                                              float* __restrict__ cs, float* __restrict__ sn) {
    __shared__ float tile[64][68];
    int bid = blockIdx.x;
    int tid = threadIdx.x;
    if (bid < 1024) {
        int w = bid >> 8, tl = bid & 255;
        int k0 = (tl >> 4) * 64, n0 = (tl & 15) * 64;
        const float* W = (w == 0) ? Wq : (w == 1) ? Wk : (w == 2) ? Wv : Wo;
#pragma unroll
        for (int p = 0; p < 4; ++p) {
            int idx = p * 256 + tid;
            int r = idx >> 4, c4 = (idx & 15) * 4;
            float4 f = *(const float4*)&W[(size_t)(k0 + r) * EE + n0 + c4];
            *(float4*)&tile[r][c4] = f;
        }
        __syncthreads();
        __bf16* out = WT + (size_t)w * EE * EE;
#pragma unroll
        for (int p = 0; p < 2; ++p) {
            int q = p * 256 + tid;
            int r = q >> 3, c8 = (q & 7) * 8;
            bf16x8 v;
#pragma unroll
            for (int j = 0; j < 8; ++j) v[j] = (__bf16)tile[c8 + j][r];
            *(bf16x8*)&out[(size_t)(n0 + r) * EE + k0 + c8] = v;
        }
    } else if (bid < 1280) {
        int i = ((bid - 1024) * 256 + tid) * 8;
        float4 a = *(const float4*)&x[i];
        float4 b = *(const float4*)&x[i + 4];
        bf16x8 v;
        v[0] = (__bf16)a.x; v[1] = (__bf16)a.y; v[2] = (__bf16)a.z; v[3] = (__bf16)a.w;
        v[4] = (__bf16)b.x; v[5] = (__bf16)b.y; v[6] = (__bf16)b.z; v[7] = (__bf16)b.w;
        *(bf16x8*)&xb[i] = v;
    } else {
        int sp = sp_ptr[0];
#pragma unroll
        for (int q = 0; q < 2; ++q) {
            int i = q * 256 + tid;       // 0..511 = h*32 + p
            int h = i >> 5, p = i & 31;
            double inv = 1.0 / pow(10000.0, (double)p / 32.0);
            double ang = (double)(sp + h) * inv;
            cs[i] = (float)cos(ang);
            sn[i] = (float)sin(ang);
        }
    }
}

// ---- fused QKV projection + RoPE, outputs (B,H,T,D) bf16 ----
__global__ __launch_bounds__(256) void k_qkv(const __bf16* __restrict__ xb, const __bf16* __restrict__ WT,
                                             const float* __restrict__ cs, const float* __restrict__ sn,
                                             __bf16* __restrict__ qws, __bf16* __restrict__ knew,
                                             __bf16* __restrict__ vnew) {
    __shared__ __bf16 a_lds[64][72];
    __shared__ __bf16 b_lds[64][72];
    int bm = blockIdx.x / 48, bn = blockIdx.x % 48;
    int wsel = bn >> 4;              // 0=q, 1=k, 2=v
    int n0 = (bn & 15) * 64;
    int m0 = bm * 64;
    const __bf16* Wt = WT + (size_t)wsel * EE * EE;
    int tid = threadIdx.x;
    int wv = tid >> 6, lane = tid & 63;
    int l16 = lane & 15, lhi = lane >> 4;

    f32x4 acc[4];
#pragma unroll
    for (int f = 0; f < 4; ++f) acc[f] = (f32x4){0.f, 0.f, 0.f, 0.f};

    for (int kt = 0; kt < 16; ++kt) {
        __syncthreads();
#pragma unroll
        for (int p = 0; p < 2; ++p) {
            int idx = p * 256 + tid;
            int r = idx >> 3, c8 = (idx & 7) * 8;
            *(bf16x8*)&a_lds[r][c8] = *(const bf16x8*)&xb[(size_t)(m0 + r) * EE + kt * 64 + c8];
            *(bf16x8*)&b_lds[r][c8] = *(const bf16x8*)&Wt[(size_t)(n0 + r) * EE + kt * 64 + c8];
        }
        __syncthreads();
        bf16x8 a0 = *(bf16x8*)&a_lds[wv * 16 + l16][lhi * 8];
        bf16x8 a1 = *(bf16x8*)&a_lds[wv * 16 + l16][32 + lhi * 8];
#pragma unroll
        for (int f = 0; f < 4; ++f) {
            bf16x8 b0 = *(bf16x8*)&b_lds[f * 16 + l16][lhi * 8];
            bf16x8 b1 = *(bf16x8*)&b_lds[f * 16 + l16][32 + lhi * 8];
            acc[f] = mfma16(a0, b0, acc[f]);
            acc[f] = mfma16(a1, b1, acc[f]);
        }
    }
    __bf16* dst = (wsel == 0) ? qws : (wsel == 1) ? knew : vnew;
#pragma unroll
    for (int f = 0; f < 4; ++f) {
#pragma unroll
        for (int r = 0; r < 4; ++r) {
            float v = acc[f][r];
            int row = m0 + wv * 16 + lhi * 4 + r;
            int ng = n0 + f * 16 + l16;
            int h = ng >> 6, d = ng & 63;
            float o = v;
            if (wsel < 2) {
                float other = __shfl_xor(v, 1);   // partner column (d^1) same row
                int pp = d >> 1;
                float c = cs[h * 32 + pp], s = sn[h * 32 + pp];
                o = ((d & 1) == 0) ? (v * c - other * s) : (other * s + v * c);
            }
            int b = row >> 6, t = row & 63;
            dst[((size_t)((b * HH + h) * TT + t)) * DD + d] = (__bf16)o;
        }
    }
}

// ---- flash-decoding attention with register prefetch ----
// grid = B*H*NSPLIT (=1024, 4 blocks/CU), block = 256 (4 waves)
// split 7 additionally handles the 64 new (masked) keys.
__global__ __launch_bounds__(256) void k_attn(const __bf16* __restrict__ qws, const __bf16* __restrict__ knew,
                                              const __bf16* __restrict__ vnew,
                                              const float* __restrict__ ck, const float* __restrict__ cv,
                                              float* __restrict__ Opart, float* __restrict__ mpart,
                                              float* __restrict__ lpart) {
    __shared__ __bf16 k_lds[64][72];    // [s][d]
    __shared__ __bf16 vT_lds[64][72];   // [d][s]
    __shared__ __bf16 p_lds[64][72];    // [t][s] (wave-local rows)
    int bh = blockIdx.x >> 3, split = blockIdx.x & 7;
    int b = bh >> 4, h = bh & 15;
    int tid = threadIdx.x, wv = tid >> 6, lane = tid & 63;
    int l16 = lane & 15, lhi = lane >> 4;
    int rr = tid >> 4, c4 = (tid & 15) * 4;   // staging coords

    // Q fragments (A operand), rows t = wv*16 + l16
    bf16x8 qf0, qf1;
    {
        const __bf16* qp = qws + ((size_t)bh * TT + (wv * 16 + l16)) * DD;
        qf0 = *(const bf16x8*)&qp[lhi * 8];
        qf1 = *(const bf16x8*)&qp[32 + lhi * 8];
    }
    f32x4 acc[4];
#pragma unroll
    for (int f = 0; f < 4; ++f) acc[f] = (f32x4){0.f, 0.f, 0.f, 0.f};
    float m[4], l[4];
#pragma unroll
    for (int r = 0; r < 4; ++r) { m[r] = -1e30f; l[r] = 0.f; }

    const float* ckb = ck + (size_t)b * 8192 * EE + h * DD;   // row stride EE floats
    const float* cvb = cv + (size_t)b * 8192 * EE + h * DD;
    int s0 = split * 512;

    auto compute = [&](bool mask) {
        // scores = Q * K^T  (M=t, N=s, K=d)
        f32x4 sf[4];
#pragma unroll
        for (int f = 0; f < 4; ++f) {
            f32x4 z = (f32x4){0.f, 0.f, 0.f, 0.f};
            bf16x8 b0 = *(bf16x8*)&k_lds[f * 16 + l16][lhi * 8];
            bf16x8 b1 = *(bf16x8*)&k_lds[f * 16 + l16][32 + lhi * 8];
            z = mfma16(qf0, b0, z);
            z = mfma16(qf1, b1, z);
            sf[f] = z;
        }
#pragma unroll
        for (int f = 0; f < 4; ++f) {
#pragma unroll
            for (int r = 0; r < 4; ++r) {
                float sv = sf[f][r] * 0.125f;
                if (mask) {
                    int t_row = wv * 16 + lhi * 4 + r;
                    int s_loc = f * 16 + l16;
                    if (s_loc > t_row) sv = -1e30f;
                }
                sf[f][r] = sv;
            }
        }
        float mt[4];
#pragma unroll
        for (int r = 0; r < 4; ++r)
            mt[r] = fmaxf(fmaxf(sf[0][r], sf[1][r]), fmaxf(sf[2][r], sf[3][r]));
#pragma unroll
        for (int off = 1; off < 16; off <<= 1) {
#pragma unroll
            for (int r = 0; r < 4; ++r) mt[r] = fmaxf(mt[r], __shfl_xor(mt[r], off));
        }
        float fac[4];
#pragma unroll
        for (int r = 0; r < 4; ++r) {
            float mn = fmaxf(m[r], mt[r]);
            fac[r] = __expf(m[r] - mn);
            m[r] = mn;
        }
        float ladd[4] = {0.f, 0.f, 0.f, 0.f};
#pragma unroll
        for (int f = 0; f < 4; ++f) {
#pragma unroll
            for (int r = 0; r < 4; ++r) {
                float pv = __expf(sf[f][r] - m[r]);
                sf[f][r] = pv;
                ladd[r] += pv;
            }
        }
#pragma unroll
        for (int off = 1; off < 16; off <<= 1) {
#pragma unroll
            for (int r = 0; r < 4; ++r) ladd[r] += __shfl_xor(ladd[r], off);
        }
#pragma unroll
        for (int r = 0; r < 4; ++r) l[r] = l[r] * fac[r] + ladd[r];
#pragma unroll
        for (int f = 0; f < 4; ++f)
#pragma unroll
            for (int r = 0; r < 4; ++r) acc[f][r] *= fac[r];
        // P -> LDS: wave-local rows, no cross-wave barrier needed
#pragma unroll
        for (int f = 0; f < 4; ++f)
#pragma unroll
            for (int r = 0; r < 4; ++r)
                p_lds[wv * 16 + lhi * 4 + r][f * 16 + l16] = (__bf16)sf[f][r];
        bf16x8 pa0 = *(bf16x8*)&p_lds[wv * 16 + l16][lhi * 8];
        bf16x8 pa1 = *(bf16x8*)&p_lds[wv * 16 + l16][32 + lhi * 8];
#pragma unroll
        for (int f = 0; f < 4; ++f) {
            bf16x8 v0 = *(bf16x8*)&vT_lds[f * 16 + l16][lhi * 8];
            bf16x8 v1 = *(bf16x8*)&vT_lds[f * 16 + l16][32 + lhi * 8];
            acc[f] = mfma16(pa0, v0, acc[f]);
            acc[f] = mfma16(pa1, v1, acc[f]);
        }
    };

    // prefetch tile 0 into registers
    float4 kreg[4], vreg[4];
#pragma unroll
    for (int p = 0; p < 4; ++p) {
        size_t off = (size_t)(s0 + p * 16 + rr) * EE + c4;
        kreg[p] = *(const float4*)&ckb[off];
        vreg[p] = *(const float4*)&cvb[off];
    }

    for (int it = 0; it < 8; ++it) {
        // write current tile regs -> LDS (convert to bf16, transpose V)
#pragma unroll
        for (int p = 0; p < 4; ++p) {
            int r = p * 16 + rr;
            bf16x4 k4 = { (__bf16)kreg[p].x, (__bf16)kreg[p].y, (__bf16)kreg[p].z, (__bf16)kreg[p].w };
            *(bf16x4*)&k_lds[r][c4] = k4;
            vT_lds[c4 + 0][r] = (__bf16)vreg[p].x;
            vT_lds[c4 + 1][r] = (__bf16)vreg[p].y;
            vT_lds[c4 + 2][r] = (__bf16)vreg[p].z;
            vT_lds[c4 + 3][r] = (__bf16)vreg[p].w;
        }
        // issue next tile's global loads (overlap with compute below)
        if (it < 7) {
#pragma unroll
            for (int p = 0; p < 4; ++p) {
                size_t off = (size_t)(s0 + (it + 1) * 64 + p * 16 + rr) * EE + c4;
                kreg[p] = *(const float4*)&ckb[off];
                vreg[p] = *(const float4*)&cvb[off];
            }
        }
        __syncthreads();
        compute(false);
        __syncthreads();   // protect LDS before next tile's writes
    }

    if (split == 7) {
        // new (masked) keys from knew/vnew (bf16)
#pragma unroll
        for (int p = 0; p < 2; ++p) {
            int idx = p * 256 + tid;
            int r = idx >> 3, c8 = (idx & 7) * 8;
            *(bf16x8*)&k_lds[r][c8] = *(const bf16x8*)&knew[((size_t)bh * TT + r) * DD + c8];
            bf16x8 vf = *(const bf16x8*)&vnew[((size_t)bh * TT + r) * DD + c8];
#pragma unroll
            for (int j = 0; j < 8; ++j) vT_lds[c8 + j][r] = vf[j];
        }
        __syncthreads();
        compute(true);
    }

    // store partials
#pragma unroll
    for (int f = 0; f < 4; ++f)
#pragma unroll
        for (int r = 0; r < 4; ++r) {
            int t = wv * 16 + lhi * 4 + r;
            int d = f * 16 + l16;
            Opart[(((size_t)split * 128 + bh) * TT + t) * DD + d] = acc[f][r];
        }
    if (l16 == 0) {
#pragma unroll
        for (int r = 0; r < 4; ++r) {
            int t = wv * 16 + lhi * 4 + r;
            mpart[((size_t)split * 128 + bh) * TT + t] = m[r];
            lpart[((size_t)split * 128 + bh) * TT + t] = l[r];
        }
    }
}

// ---- combine split partials -> ctx bf16 (row-major tokens x E) ----
__global__ __launch_bounds__(256) void k_combine(const float* __restrict__ Opart, const float* __restrict__ mpart,
                                                 const float* __restrict__ lpart, __bf16* __restrict__ ctxb) {
    int idx = blockIdx.x * 256 + threadIdx.x;   // B*H*T*D = 524288
    int d = idx & 63, t = (idx >> 6) & 63, bh = idx >> 12;
    float ms[NSPLIT], ls[NSPLIT];
    float mg = -1e30f;
#pragma unroll
    for (int s = 0; s < NSPLIT; ++s) {
        ms[s] = mpart[((size_t)s * 128 + bh) * TT + t];
        ls[s] = lpart[((size_t)s * 128 + bh) * TT + t];
        mg = fmaxf(mg, ms[s]);
    }
    float den = 0.f, num = 0.f;
#pragma unroll
    for (int s = 0; s < NSPLIT; ++s) {
        float w = __expf(ms[s] - mg);
        den += ls[s] * w;
        num += Opart[(((size_t)s * 128 + bh) * TT + t) * DD + d] * w;
    }
    float ctx = num / den;
    int b = bh >> 4, hh = bh & 15;
    ctxb[(size_t)(b * TT + t) * EE + hh * DD + d] = (__bf16)ctx;
}

// ---- output projection: out = ctx @ Wo ----
__global__ __launch_bounds__(256) void k_oproj(const __bf16* __restrict__ ctxb, const __bf16* __restrict__ WoT,
                                               float* __restrict__ out) {
    __shared__ __bf16 a_lds[64][72];
    __shared__ __bf16 b_lds[64][72];
    int bm = blockIdx.x >> 4, bn = blockIdx.x & 15;
    int n0 = bn * 64, m0 = bm * 64;
    int tid = threadIdx.x;
    int wv = tid >> 6, lane = tid & 63;
    int l16 = lane & 15, lhi = lane >> 4;
    f32x4 acc[4];
#pragma unroll
    for (int f = 0; f < 4; ++f) acc[f] = (f32x4){0.f, 0.f, 0.f, 0.f};

    for (int kt = 0; kt < 16; ++kt) {
        __syncthreads();
#pragma unroll
        for (int p = 0; p < 2; ++p) {
            int idx = p * 256 + tid;
            int r = idx >> 3, c8 = (idx & 7) * 8;
            *(bf16x8*)&a_lds[r][c8] = *(const bf16x8*)&ctxb[(size_t)(m0 + r) * EE + kt * 64 + c8];
            *(bf16x8*)&b_lds[r][c8] = *(const bf16x8*)&WoT[(size_t)(n0 + r) * EE + kt * 64 + c8];
        }
        __syncthreads();
        bf16x8 a0 = *(bf16x8*)&a_lds[wv * 16 + l16][lhi * 8];
        bf16x8 a1 = *(bf16x8*)&a_lds[wv * 16 + l16][32 + lhi * 8];
#pragma unroll
        for (int f = 0; f < 4; ++f) {
            bf16x8 b0 = *(bf16x8*)&b_lds[f * 16 + l16][lhi * 8];
            bf16x8 b1 = *(bf16x8*)&b_lds[f * 16 + l16][32 + lhi * 8];
            acc[f] = mfma16(a0, b0, acc[f]);
            acc[f] = mfma16(a1, b1, acc[f]);
        }
    }
#pragma unroll
    for (int f = 0; f < 4; ++f)
#pragma unroll
        for (int r = 0; r < 4; ++r) {
            int row = m0 + wv * 16 + lhi * 4 + r;
            out[(size_t)row * EE + n0 + f * 16 + l16] = acc[f][r];
        }
}

extern "C" void kernel_launch(void* const* d_in, const int* in_sizes, int n_in,
                              void* d_out, int out_size, void* d_ws, size_t ws_size,
                              hipStream_t stream) {
    const float* x  = (const float*)d_in[0];
    const float* ck = (const float*)d_in[1];
    const float* cv = (const float*)d_in[2];
    const float* Wq = (const float*)d_in[3];
    const float* Wk = (const float*)d_in[4];
    const float* Wv = (const float*)d_in[5];
    const float* Wo = (const float*)d_in[6];
    const int* sp   = (const int*)d_in[7];
    float* out = (float*)d_out;

    char* p = (char*)d_ws;
    float* cs = (float*)p;              p += 2048;
    float* sn = (float*)p;              p += 2048;
    __bf16* xb = (__bf16*)p;            p += (size_t)512 * 1024 * 2;
    __bf16* WT = (__bf16*)p;            p += (size_t)4 * 1024 * 1024 * 2;
    __bf16* qws = (__bf16*)p;           p += (size_t)524288 * 2;
    __bf16* knew = (__bf16*)p;          p += (size_t)524288 * 2;
    __bf16* vnew = (__bf16*)p;          p += (size_t)524288 * 2;
    float* Opart = (float*)p;           p += (size_t)NSPLIT * 128 * 64 * 64 * 4;
    float* mpart = (float*)p;           p += (size_t)NSPLIT * 8192 * 4;
    float* lpart = (float*)p;           p += (size_t)NSPLIT * 8192 * 4;
    __bf16* ctxb = (__bf16*)p;          p += (size_t)524288 * 2;

    k_prep<<<1281, 256, 0, stream>>>(Wq, Wk, Wv, Wo, x, sp, WT, xb, cs, sn);
    k_qkv<<<384, 256, 0, stream>>>(xb, WT, cs, sn, qws, knew, vnew);
    k_attn<<<BB * HH * NSPLIT, 256, 0, stream>>>(qws, knew, vnew, ck, cv, Opart, mpart, lpart);
    k_combine<<<2048, 256, 0, stream>>>(Opart, mpart, lpart, ctxb);
    k_oproj<<<128, 256, 0, stream>>>(ctxb, WT + (size_t)3 * 1024 * 1024, out);
}

// Round 3
// 91.924 us; speedup vs baseline: 1.3356x; 1.1055x over previous
//
#include <hip/hip_runtime.h>
#include <hip/hip_bf16.h>
#include <math.h>

typedef __attribute__((ext_vector_type(8))) __bf16 bf16x8;
typedef __attribute__((ext_vector_type(4))) __bf16 bf16x4;
typedef __attribute__((ext_vector_type(4))) float f32x4;

#define EE 1024
#define HH 16
#define DD 64
#define BB 8
#define TT 64
#define NSPLIT 8

__device__ __forceinline__ f32x4 mfma16(bf16x8 a, bf16x8 b, f32x4 c) {
    return __builtin_amdgcn_mfma_f32_16x16x32_bf16(a, b, c, 0, 0, 0);
}

// ---- fused prep: weight transpose+convert, x convert, RoPE tables ----
__global__ __launch_bounds__(256) void k_prep(const float* __restrict__ Wq, const float* __restrict__ Wk,
                                              const float* __restrict__ Wv, const float* __restrict__ Wo,
                                              const float* __restrict__ x, const int* __restrict__ sp_ptr,
                                              __bf16* __restrict__ WT, __bf16* __restrict__ xb,
                                              float* __restrict__ cs, float* __restrict__ sn) {
    __shared__ float tile[64][68];
    int bid = blockIdx.x;
    int tid = threadIdx.x;
    if (bid < 1024) {
        int w = bid >> 8, tl = bid & 255;
        int k0 = (tl >> 4) * 64, n0 = (tl & 15) * 64;
        const float* W = (w == 0) ? Wq : (w == 1) ? Wk : (w == 2) ? Wv : Wo;
#pragma unroll
        for (int p = 0; p < 4; ++p) {
            int idx = p * 256 + tid;
            int r = idx >> 4, c4 = (idx & 15) * 4;
            float4 f = *(const float4*)&W[(size_t)(k0 + r) * EE + n0 + c4];
            *(float4*)&tile[r][c4] = f;
        }
        __syncthreads();
        __bf16* out = WT + (size_t)w * EE * EE;
#pragma unroll
        for (int p = 0; p < 2; ++p) {
            int q = p * 256 + tid;
            int r = q >> 3, c8 = (q & 7) * 8;
            bf16x8 v;
#pragma unroll
            for (int j = 0; j < 8; ++j) v[j] = (__bf16)tile[c8 + j][r];
            *(bf16x8*)&out[(size_t)(n0 + r) * EE + k0 + c8] = v;
        }
    } else if (bid < 1280) {
        int i = ((bid - 1024) * 256 + tid) * 8;
        float4 a = *(const float4*)&x[i];
        float4 b = *(const float4*)&x[i + 4];
        bf16x8 v;
        v[0] = (__bf16)a.x; v[1] = (__bf16)a.y; v[2] = (__bf16)a.z; v[3] = (__bf16)a.w;
        v[4] = (__bf16)b.x; v[5] = (__bf16)b.y; v[6] = (__bf16)b.z; v[7] = (__bf16)b.w;
        *(bf16x8*)&xb[i] = v;
    } else {
        int sp = sp_ptr[0];
#pragma unroll
        for (int q = 0; q < 2; ++q) {
            int i = q * 256 + tid;       // 0..511 = h*32 + p
            int h = i >> 5, p = i & 31;
            double inv = 1.0 / pow(10000.0, (double)p / 32.0);
            double ang = (double)(sp + h) * inv;
            cs[i] = (float)cos(ang);
            sn[i] = (float)sin(ang);
        }
    }
}

// ---- fused QKV projection + RoPE with register-prefetch pipeline ----
__global__ __launch_bounds__(256) void k_qkv(const __bf16* __restrict__ xb, const __bf16* __restrict__ WT,
                                             const float* __restrict__ cs, const float* __restrict__ sn,
                                             __bf16* __restrict__ qws, __bf16* __restrict__ knew,
                                             __bf16* __restrict__ vnew) {
    __shared__ __bf16 a_lds[64][72];
    __shared__ __bf16 b_lds[64][72];
    int bm = blockIdx.x / 48, bn = blockIdx.x % 48;
    int wsel = bn >> 4;              // 0=q, 1=k, 2=v
    int n0 = (bn & 15) * 64;
    int m0 = bm * 64;
    const __bf16* Wt = WT + (size_t)wsel * EE * EE;
    int tid = threadIdx.x;
    int wv = tid >> 6, lane = tid & 63;
    int l16 = lane & 15, lhi = lane >> 4;
    int r0 = tid >> 3, c8 = (tid & 7) * 8;    // staging: rows r0 and r0+32

    f32x4 acc[4];
#pragma unroll
    for (int f = 0; f < 4; ++f) acc[f] = (f32x4){0.f, 0.f, 0.f, 0.f};

    // prologue: prefetch kt=0
    bf16x8 ar0 = *(const bf16x8*)&xb[(size_t)(m0 + r0) * EE + c8];
    bf16x8 ar1 = *(const bf16x8*)&xb[(size_t)(m0 + 32 + r0) * EE + c8];
    bf16x8 br0 = *(const bf16x8*)&Wt[(size_t)(n0 + r0) * EE + c8];
    bf16x8 br1 = *(const bf16x8*)&Wt[(size_t)(n0 + 32 + r0) * EE + c8];

    for (int kt = 0; kt < 16; ++kt) {
        __syncthreads();             // previous compute done reading LDS
        *(bf16x8*)&a_lds[r0][c8] = ar0;
        *(bf16x8*)&a_lds[32 + r0][c8] = ar1;
        *(bf16x8*)&b_lds[r0][c8] = br0;
        *(bf16x8*)&b_lds[32 + r0][c8] = br1;
        if (kt < 15) {               // issue next K-step loads; overlap with MFMA below
            int ko = (kt + 1) * 64;
            ar0 = *(const bf16x8*)&xb[(size_t)(m0 + r0) * EE + ko + c8];
            ar1 = *(const bf16x8*)&xb[(size_t)(m0 + 32 + r0) * EE + ko + c8];
            br0 = *(const bf16x8*)&Wt[(size_t)(n0 + r0) * EE + ko + c8];
            br1 = *(const bf16x8*)&Wt[(size_t)(n0 + 32 + r0) * EE + ko + c8];
        }
        __syncthreads();
        bf16x8 a0 = *(bf16x8*)&a_lds[wv * 16 + l16][lhi * 8];
        bf16x8 a1 = *(bf16x8*)&a_lds[wv * 16 + l16][32 + lhi * 8];
#pragma unroll
        for (int f = 0; f < 4; ++f) {
            bf16x8 b0 = *(bf16x8*)&b_lds[f * 16 + l16][lhi * 8];
            bf16x8 b1 = *(bf16x8*)&b_lds[f * 16 + l16][32 + lhi * 8];
            acc[f] = mfma16(a0, b0, acc[f]);
            acc[f] = mfma16(a1, b1, acc[f]);
        }
    }
    __bf16* dst = (wsel == 0) ? qws : (wsel == 1) ? knew : vnew;
#pragma unroll
    for (int f = 0; f < 4; ++f) {
#pragma unroll
        for (int r = 0; r < 4; ++r) {
            float v = acc[f][r];
            int row = m0 + wv * 16 + lhi * 4 + r;
            int ng = n0 + f * 16 + l16;
            int h = ng >> 6, d = ng & 63;
            float o = v;
            if (wsel < 2) {
                float other = __shfl_xor(v, 1);   // partner column (d^1) same row
                int pp = d >> 1;
                float c = cs[h * 32 + pp], s = sn[h * 32 + pp];
                o = ((d & 1) == 0) ? (v * c - other * s) : (other * s + v * c);
            }
            int b = row >> 6, t = row & 63;
            dst[((size_t)((b * HH + h) * TT + t)) * DD + d] = (__bf16)o;
        }
    }
}

// ---- flash-decoding attention with register prefetch ----
// grid = B*H*NSPLIT (=1024, 4 blocks/CU), block = 256 (4 waves)
// split 7 additionally handles the 64 new (masked) keys.
__global__ __launch_bounds__(256, 4) void k_attn(const __bf16* __restrict__ qws, const __bf16* __restrict__ knew,
                                                 const __bf16* __restrict__ vnew,
                                                 const float* __restrict__ ck, const float* __restrict__ cv,
                                                 __bf16* __restrict__ Opart, float2* __restrict__ mlpart) {
    __shared__ __bf16 k_lds[64][72];    // [s][d]
    __shared__ __bf16 vT_lds[64][72];   // [d][s]
    __shared__ __bf16 p_lds[64][72];    // [t][s] (wave-local rows)
    int bh = blockIdx.x >> 3, split = blockIdx.x & 7;
    int b = bh >> 4, h = bh & 15;
    int tid = threadIdx.x, wv = tid >> 6, lane = tid & 63;
    int l16 = lane & 15, lhi = lane >> 4;
    int rr = tid >> 4, c4 = (tid & 15) * 4;   // staging coords

    bf16x8 qf0, qf1;
    {
        const __bf16* qp = qws + ((size_t)bh * TT + (wv * 16 + l16)) * DD;
        qf0 = *(const bf16x8*)&qp[lhi * 8];
        qf1 = *(const bf16x8*)&qp[32 + lhi * 8];
    }
    f32x4 acc[4];
#pragma unroll
    for (int f = 0; f < 4; ++f) acc[f] = (f32x4){0.f, 0.f, 0.f, 0.f};
    float m[4], l[4];
#pragma unroll
    for (int r = 0; r < 4; ++r) { m[r] = -1e30f; l[r] = 0.f; }

    const float* ckb = ck + (size_t)b * 8192 * EE + h * DD;   // row stride EE floats
    const float* cvb = cv + (size_t)b * 8192 * EE + h * DD;
    int s0 = split * 512;

    auto compute = [&](bool mask) {
        f32x4 sf[4];
#pragma unroll
        for (int f = 0; f < 4; ++f) {
            f32x4 z = (f32x4){0.f, 0.f, 0.f, 0.f};
            bf16x8 b0 = *(bf16x8*)&k_lds[f * 16 + l16][lhi * 8];
            bf16x8 b1 = *(bf16x8*)&k_lds[f * 16 + l16][32 + lhi * 8];
            z = mfma16(qf0, b0, z);
            z = mfma16(qf1, b1, z);
            sf[f] = z;
        }
#pragma unroll
        for (int f = 0; f < 4; ++f) {
#pragma unroll
            for (int r = 0; r < 4; ++r) {
                float sv = sf[f][r] * 0.125f;
                if (mask) {
                    int t_row = wv * 16 + lhi * 4 + r;
                    int s_loc = f * 16 + l16;
                    if (s_loc > t_row) sv = -1e30f;
                }
                sf[f][r] = sv;
            }
        }
        float mt[4];
#pragma unroll
        for (int r = 0; r < 4; ++r)
            mt[r] = fmaxf(fmaxf(sf[0][r], sf[1][r]), fmaxf(sf[2][r], sf[3][r]));
#pragma unroll
        for (int off = 1; off < 16; off <<= 1) {
#pragma unroll
            for (int r = 0; r < 4; ++r) mt[r] = fmaxf(mt[r], __shfl_xor(mt[r], off));
        }
        float fac[4];
#pragma unroll
        for (int r = 0; r < 4; ++r) {
            float mn = fmaxf(m[r], mt[r]);
            fac[r] = __expf(m[r] - mn);
            m[r] = mn;
        }
        float ladd[4] = {0.f, 0.f, 0.f, 0.f};
#pragma unroll
        for (int f = 0; f < 4; ++f) {
#pragma unroll
            for (int r = 0; r < 4; ++r) {
                float pv = __expf(sf[f][r] - m[r]);
                sf[f][r] = pv;
                ladd[r] += pv;
            }
        }
#pragma unroll
        for (int off = 1; off < 16; off <<= 1) {
#pragma unroll
            for (int r = 0; r < 4; ++r) ladd[r] += __shfl_xor(ladd[r], off);
        }
#pragma unroll
        for (int r = 0; r < 4; ++r) l[r] = l[r] * fac[r] + ladd[r];
#pragma unroll
        for (int f = 0; f < 4; ++f)
#pragma unroll
            for (int r = 0; r < 4; ++r) acc[f][r] *= fac[r];
#pragma unroll
        for (int f = 0; f < 4; ++f)
#pragma unroll
            for (int r = 0; r < 4; ++r)
                p_lds[wv * 16 + lhi * 4 + r][f * 16 + l16] = (__bf16)sf[f][r];
        bf16x8 pa0 = *(bf16x8*)&p_lds[wv * 16 + l16][lhi * 8];
        bf16x8 pa1 = *(bf16x8*)&p_lds[wv * 16 + l16][32 + lhi * 8];
#pragma unroll
        for (int f = 0; f < 4; ++f) {
            bf16x8 v0 = *(bf16x8*)&vT_lds[f * 16 + l16][lhi * 8];
            bf16x8 v1 = *(bf16x8*)&vT_lds[f * 16 + l16][32 + lhi * 8];
            acc[f] = mfma16(pa0, v0, acc[f]);
            acc[f] = mfma16(pa1, v1, acc[f]);
        }
    };

    float4 kreg[4], vreg[4];
#pragma unroll
    for (int p = 0; p < 4; ++p) {
        size_t off = (size_t)(s0 + p * 16 + rr) * EE + c4;
        kreg[p] = *(const float4*)&ckb[off];
        vreg[p] = *(const float4*)&cvb[off];
    }

    for (int it = 0; it < 8; ++it) {
#pragma unroll
        for (int p = 0; p < 4; ++p) {
            int r = p * 16 + rr;
            bf16x4 k4 = { (__bf16)kreg[p].x, (__bf16)kreg[p].y, (__bf16)kreg[p].z, (__bf16)kreg[p].w };
            *(bf16x4*)&k_lds[r][c4] = k4;
            vT_lds[c4 + 0][r] = (__bf16)vreg[p].x;
            vT_lds[c4 + 1][r] = (__bf16)vreg[p].y;
            vT_lds[c4 + 2][r] = (__bf16)vreg[p].z;
            vT_lds[c4 + 3][r] = (__bf16)vreg[p].w;
        }
        if (it < 7) {
#pragma unroll
            for (int p = 0; p < 4; ++p) {
                size_t off = (size_t)(s0 + (it + 1) * 64 + p * 16 + rr) * EE + c4;
                kreg[p] = *(const float4*)&ckb[off];
                vreg[p] = *(const float4*)&cvb[off];
            }
        }
        __syncthreads();
        compute(false);
        __syncthreads();
    }

    if (split == 7) {
#pragma unroll
        for (int p = 0; p < 2; ++p) {
            int idx = p * 256 + tid;
            int r = idx >> 3, c8 = (idx & 7) * 8;
            *(bf16x8*)&k_lds[r][c8] = *(const bf16x8*)&knew[((size_t)bh * TT + r) * DD + c8];
            bf16x8 vf = *(const bf16x8*)&vnew[((size_t)bh * TT + r) * DD + c8];
#pragma unroll
            for (int j = 0; j < 8; ++j) vT_lds[c8 + j][r] = vf[j];
        }
        __syncthreads();
        compute(true);
    }

    // store partials (bf16 O, float2 m/l)
#pragma unroll
    for (int f = 0; f < 4; ++f)
#pragma unroll
        for (int r = 0; r < 4; ++r) {
            int t = wv * 16 + lhi * 4 + r;
            int d = f * 16 + l16;
            Opart[(((size_t)split * 128 + bh) * TT + t) * DD + d] = (__bf16)acc[f][r];
        }
    if (l16 == 0) {
#pragma unroll
        for (int r = 0; r < 4; ++r) {
            int t = wv * 16 + lhi * 4 + r;
            mlpart[((size_t)split * 128 + bh) * TT + t] = make_float2(m[r], l[r]);
        }
    }
}

// ---- combine split partials -> ctx bf16 (row-major tokens x E) ----
__global__ __launch_bounds__(256) void k_combine(const __bf16* __restrict__ Opart, const float2* __restrict__ mlpart,
                                                 __bf16* __restrict__ ctxb) {
    int idx = blockIdx.x * 256 + threadIdx.x;   // B*H*T*D = 524288
    int d = idx & 63, t = (idx >> 6) & 63, bh = idx >> 12;
    float ms[NSPLIT], ls[NSPLIT];
    float mg = -1e30f;
#pragma unroll
    for (int s = 0; s < NSPLIT; ++s) {
        float2 ml = mlpart[((size_t)s * 128 + bh) * TT + t];
        ms[s] = ml.x; ls[s] = ml.y;
        mg = fmaxf(mg, ms[s]);
    }
    float den = 0.f, num = 0.f;
#pragma unroll
    for (int s = 0; s < NSPLIT; ++s) {
        float w = __expf(ms[s] - mg);
        den += ls[s] * w;
        num += (float)Opart[(((size_t)s * 128 + bh) * TT + t) * DD + d] * w;
    }
    float ctx = num / den;
    int b = bh >> 4, hh = bh & 15;
    ctxb[(size_t)(b * TT + t) * EE + hh * DD + d] = (__bf16)ctx;
}

// ---- output projection: out = ctx @ Wo (register-prefetch pipeline) ----
__global__ __launch_bounds__(256) void k_oproj(const __bf16* __restrict__ ctxb, const __bf16* __restrict__ WoT,
                                               float* __restrict__ out) {
    __shared__ __bf16 a_lds[64][72];
    __shared__ __bf16 b_lds[64][72];
    int bm = blockIdx.x >> 4, bn = blockIdx.x & 15;
    int n0 = bn * 64, m0 = bm * 64;
    int tid = threadIdx.x;
    int wv = tid >> 6, lane = tid & 63;
    int l16 = lane & 15, lhi = lane >> 4;
    int r0 = tid >> 3, c8 = (tid & 7) * 8;
    f32x4 acc[4];
#pragma unroll
    for (int f = 0; f < 4; ++f) acc[f] = (f32x4){0.f, 0.f, 0.f, 0.f};

    bf16x8 ar0 = *(const bf16x8*)&ctxb[(size_t)(m0 + r0) * EE + c8];
    bf16x8 ar1 = *(const bf16x8*)&ctxb[(size_t)(m0 + 32 + r0) * EE + c8];
    bf16x8 br0 = *(const bf16x8*)&WoT[(size_t)(n0 + r0) * EE + c8];
    bf16x8 br1 = *(const bf16x8*)&WoT[(size_t)(n0 + 32 + r0) * EE + c8];

    for (int kt = 0; kt < 16; ++kt) {
        __syncthreads();
        *(bf16x8*)&a_lds[r0][c8] = ar0;
        *(bf16x8*)&a_lds[32 + r0][c8] = ar1;
        *(bf16x8*)&b_lds[r0][c8] = br0;
        *(bf16x8*)&b_lds[32 + r0][c8] = br1;
        if (kt < 15) {
            int ko = (kt + 1) * 64;
            ar0 = *(const bf16x8*)&ctxb[(size_t)(m0 + r0) * EE + ko + c8];
            ar1 = *(const bf16x8*)&ctxb[(size_t)(m0 + 32 + r0) * EE + ko + c8];
            br0 = *(const bf16x8*)&WoT[(size_t)(n0 + r0) * EE + ko + c8];
            br1 = *(const bf16x8*)&WoT[(size_t)(n0 + 32 + r0) * EE + ko + c8];
        }
        __syncthreads();
        bf16x8 a0 = *(bf16x8*)&a_lds[wv * 16 + l16][lhi * 8];
        bf16x8 a1 = *(bf16x8*)&a_lds[wv * 16 + l16][32 + lhi * 8];
#pragma unroll
        for (int f = 0; f < 4; ++f) {
            bf16x8 b0 = *(bf16x8*)&b_lds[f * 16 + l16][lhi * 8];
            bf16x8 b1 = *(bf16x8*)&b_lds[f * 16 + l16][32 + lhi * 8];
            acc[f] = mfma16(a0, b0, acc[f]);
            acc[f] = mfma16(a1, b1, acc[f]);
        }
    }
#pragma unroll
    for (int f = 0; f < 4; ++f)
#pragma unroll
        for (int r = 0; r < 4; ++r) {
            int row = m0 + wv * 16 + lhi * 4 + r;
            out[(size_t)row * EE + n0 + f * 16 + l16] = acc[f][r];
        }
}

extern "C" void kernel_launch(void* const* d_in, const int* in_sizes, int n_in,
                              void* d_out, int out_size, void* d_ws, size_t ws_size,
                              hipStream_t stream) {
    const float* x  = (const float*)d_in[0];
    const float* ck = (const float*)d_in[1];
    const float* cv = (const float*)d_in[2];
    const float* Wq = (const float*)d_in[3];
    const float* Wk = (const float*)d_in[4];
    const float* Wv = (const float*)d_in[5];
    const float* Wo = (const float*)d_in[6];
    const int* sp   = (const int*)d_in[7];
    float* out = (float*)d_out;

    char* p = (char*)d_ws;
    float* cs = (float*)p;              p += 2048;
    float* sn = (float*)p;              p += 2048;
    __bf16* xb = (__bf16*)p;            p += (size_t)512 * 1024 * 2;
    __bf16* WT = (__bf16*)p;            p += (size_t)4 * 1024 * 1024 * 2;
    __bf16* qws = (__bf16*)p;           p += (size_t)524288 * 2;
    __bf16* knew = (__bf16*)p;          p += (size_t)524288 * 2;
    __bf16* vnew = (__bf16*)p;          p += (size_t)524288 * 2;
    __bf16* Opart = (__bf16*)p;         p += (size_t)NSPLIT * 128 * 64 * 64 * 2;
    float2* mlpart = (float2*)p;        p += (size_t)NSPLIT * 8192 * 8;
    __bf16* ctxb = (__bf16*)p;          p += (size_t)524288 * 2;

    k_prep<<<1281, 256, 0, stream>>>(Wq, Wk, Wv, Wo, x, sp, WT, xb, cs, sn);
    k_qkv<<<384, 256, 0, stream>>>(xb, WT, cs, sn, qws, knew, vnew);
    k_attn<<<BB * HH * NSPLIT, 256, 0, stream>>>(qws, knew, vnew, ck, cv, Opart, mlpart);
    k_combine<<<2048, 256, 0, stream>>>(Opart, mlpart, ctxb);
    k_oproj<<<128, 256, 0, stream>>>(ctxb, WT + (size_t)3 * 1024 * 1024, out);
}

// Round 4
// 87.354 us; speedup vs baseline: 1.4054x; 1.0523x over previous
//
#include <hip/hip_runtime.h>
#include <hip/hip_bf16.h>
#include <math.h>

typedef __attribute__((ext_vector_type(8))) __bf16 bf16x8;
typedef __attribute__((ext_vector_type(4))) __bf16 bf16x4;
typedef __attribute__((ext_vector_type(4))) float f32x4;

#define EE 1024
#define HH 16
#define DD 64
#define BB 8
#define TT 64
#define NSPLIT 8

__device__ __forceinline__ f32x4 mfma16(bf16x8 a, bf16x8 b, f32x4 c) {
    return __builtin_amdgcn_mfma_f32_16x16x32_bf16(a, b, c, 0, 0, 0);
}

// ---- fused prep: weight transpose+convert, x convert, RoPE tables ----
__global__ __launch_bounds__(256) void k_prep(const float* __restrict__ Wq, const float* __restrict__ Wk,
                                              const float* __restrict__ Wv, const float* __restrict__ Wo,
                                              const float* __restrict__ x, const int* __restrict__ sp_ptr,
                                              __bf16* __restrict__ WT, __bf16* __restrict__ xb,
                                              float* __restrict__ cs, float* __restrict__ sn) {
    __shared__ float tile[64][68];
    int bid = blockIdx.x;
    int tid = threadIdx.x;
    if (bid < 1024) {
        int w = bid >> 8, tl = bid & 255;
        int k0 = (tl >> 4) * 64, n0 = (tl & 15) * 64;
        const float* W = (w == 0) ? Wq : (w == 1) ? Wk : (w == 2) ? Wv : Wo;
#pragma unroll
        for (int p = 0; p < 4; ++p) {
            int idx = p * 256 + tid;
            int r = idx >> 4, c4 = (idx & 15) * 4;
            float4 f = *(const float4*)&W[(size_t)(k0 + r) * EE + n0 + c4];
            *(float4*)&tile[r][c4] = f;
        }
        __syncthreads();
        __bf16* out = WT + (size_t)w * EE * EE;
#pragma unroll
        for (int p = 0; p < 2; ++p) {
            int q = p * 256 + tid;
            int r = q >> 3, c8 = (q & 7) * 8;
            bf16x8 v;
#pragma unroll
            for (int j = 0; j < 8; ++j) v[j] = (__bf16)tile[c8 + j][r];
            *(bf16x8*)&out[(size_t)(n0 + r) * EE + k0 + c8] = v;
        }
    } else if (bid < 1280) {
        int i = ((bid - 1024) * 256 + tid) * 8;
        float4 a = *(const float4*)&x[i];
        float4 b = *(const float4*)&x[i + 4];
        bf16x8 v;
        v[0] = (__bf16)a.x; v[1] = (__bf16)a.y; v[2] = (__bf16)a.z; v[3] = (__bf16)a.w;
        v[4] = (__bf16)b.x; v[5] = (__bf16)b.y; v[6] = (__bf16)b.z; v[7] = (__bf16)b.w;
        *(bf16x8*)&xb[i] = v;
    } else {
        int sp = sp_ptr[0];
#pragma unroll
        for (int q = 0; q < 2; ++q) {
            int i = q * 256 + tid;       // 0..511 = h*32 + p
            int h = i >> 5, p = i & 31;
            double inv = 1.0 / pow(10000.0, (double)p / 32.0);
            double ang = (double)(sp + h) * inv;
            cs[i] = (float)cos(ang);
            sn[i] = (float)sin(ang);
        }
    }
}

// ---- fused QKV projection + RoPE, register-prefetch, XCD-swizzled ----
__global__ __launch_bounds__(256) void k_qkv(const __bf16* __restrict__ xb, const __bf16* __restrict__ WT,
                                             const float* __restrict__ cs, const float* __restrict__ sn,
                                             __bf16* __restrict__ qws, __bf16* __restrict__ knew,
                                             __bf16* __restrict__ vnew) {
    __shared__ __bf16 a_lds[64][72];
    __shared__ __bf16 b_lds[64][72];
    // XCD-aware: xcd owns 6 consecutive bn panels; bm iterates inside -> W panel stays in this XCD's L2
    int xcd = blockIdx.x & 7, idx = blockIdx.x >> 3;
    int bn = xcd * 6 + idx % 6;
    int bm = idx / 6;
    int wsel = bn >> 4;              // 0=q, 1=k, 2=v
    int n0 = (bn & 15) * 64;
    int m0 = bm * 64;
    const __bf16* Wt = WT + (size_t)wsel * EE * EE;
    int tid = threadIdx.x;
    int wv = tid >> 6, lane = tid & 63;
    int l16 = lane & 15, lhi = lane >> 4;
    int r0 = tid >> 3, c8 = (tid & 7) * 8;    // staging: rows r0 and r0+32

    f32x4 acc[4];
#pragma unroll
    for (int f = 0; f < 4; ++f) acc[f] = (f32x4){0.f, 0.f, 0.f, 0.f};

    bf16x8 ar0 = *(const bf16x8*)&xb[(size_t)(m0 + r0) * EE + c8];
    bf16x8 ar1 = *(const bf16x8*)&xb[(size_t)(m0 + 32 + r0) * EE + c8];
    bf16x8 br0 = *(const bf16x8*)&Wt[(size_t)(n0 + r0) * EE + c8];
    bf16x8 br1 = *(const bf16x8*)&Wt[(size_t)(n0 + 32 + r0) * EE + c8];

    for (int kt = 0; kt < 16; ++kt) {
        __syncthreads();
        *(bf16x8*)&a_lds[r0][c8] = ar0;
        *(bf16x8*)&a_lds[32 + r0][c8] = ar1;
        *(bf16x8*)&b_lds[r0][c8] = br0;
        *(bf16x8*)&b_lds[32 + r0][c8] = br1;
        if (kt < 15) {
            int ko = (kt + 1) * 64;
            ar0 = *(const bf16x8*)&xb[(size_t)(m0 + r0) * EE + ko + c8];
            ar1 = *(const bf16x8*)&xb[(size_t)(m0 + 32 + r0) * EE + ko + c8];
            br0 = *(const bf16x8*)&Wt[(size_t)(n0 + r0) * EE + ko + c8];
            br1 = *(const bf16x8*)&Wt[(size_t)(n0 + 32 + r0) * EE + ko + c8];
        }
        __syncthreads();
        bf16x8 a0 = *(bf16x8*)&a_lds[wv * 16 + l16][lhi * 8];
        bf16x8 a1 = *(bf16x8*)&a_lds[wv * 16 + l16][32 + lhi * 8];
#pragma unroll
        for (int f = 0; f < 4; ++f) {
            bf16x8 b0 = *(bf16x8*)&b_lds[f * 16 + l16][lhi * 8];
            bf16x8 b1 = *(bf16x8*)&b_lds[f * 16 + l16][32 + lhi * 8];
            acc[f] = mfma16(a0, b0, acc[f]);
            acc[f] = mfma16(a1, b1, acc[f]);
        }
    }
    __bf16* dst = (wsel == 0) ? qws : (wsel == 1) ? knew : vnew;
#pragma unroll
    for (int f = 0; f < 4; ++f) {
#pragma unroll
        for (int r = 0; r < 4; ++r) {
            float v = acc[f][r];
            int row = m0 + wv * 16 + lhi * 4 + r;
            int ng = n0 + f * 16 + l16;
            int h = ng >> 6, d = ng & 63;
            float o = v;
            if (wsel < 2) {
                float other = __shfl_xor(v, 1);   // partner column (d^1) same row
                int pp = d >> 1;
                float c = cs[h * 32 + pp], s = sn[h * 32 + pp];
                o = ((d & 1) == 0) ? (v * c - other * s) : (other * s + v * c);
            }
            int b = row >> 6, t = row & 63;
            dst[((size_t)((b * HH + h) * TT + t)) * DD + d] = (__bf16)o;
        }
    }
}

// ---- flash-decoding attention: reg prefetch + in-register V transpose ----
// grid = B*H*NSPLIT (=1024, 4 blocks/CU), block = 256 (4 waves)
__global__ __launch_bounds__(256, 4) void k_attn(const __bf16* __restrict__ qws, const __bf16* __restrict__ knew,
                                                 const __bf16* __restrict__ vnew,
                                                 const float* __restrict__ ck, const float* __restrict__ cv,
                                                 __bf16* __restrict__ Opart, float2* __restrict__ mlpart) {
    __shared__ __bf16 k_lds[64][72];    // [s][d] - wide row writes, b128 reads
    __shared__ __bf16 vT_lds[64][68];   // [d][s] - b64 writes (in-reg transposed), read2_b64 reads
    __shared__ __bf16 p_lds[64][72];    // [t][s] (wave-local rows)
    int bh = blockIdx.x >> 3, split = blockIdx.x & 7;
    int b = bh >> 4, h = bh & 15;
    int tid = threadIdx.x, wv = tid >> 6, lane = tid & 63;
    int l16 = lane & 15, lhi = lane >> 4;
    int g = tid >> 4, m4 = (tid & 15) * 4;   // staging coords

    bf16x8 qf0, qf1;
    {
        const __bf16* qp = qws + ((size_t)bh * TT + (wv * 16 + l16)) * DD;
        qf0 = *(const bf16x8*)&qp[lhi * 8];
        qf1 = *(const bf16x8*)&qp[32 + lhi * 8];
    }
    f32x4 acc[4];
#pragma unroll
    for (int f = 0; f < 4; ++f) acc[f] = (f32x4){0.f, 0.f, 0.f, 0.f};
    float m[4], l[4];
#pragma unroll
    for (int r = 0; r < 4; ++r) { m[r] = -1e30f; l[r] = 0.f; }

    const float* ckb = ck + (size_t)b * 8192 * EE + h * DD;   // row stride EE floats
    const float* cvb = cv + (size_t)b * 8192 * EE + h * DD;
    int s0 = split * 512;

    auto compute = [&](bool mask) {
        f32x4 sf[4];
#pragma unroll
        for (int f = 0; f < 4; ++f) {
            f32x4 z = (f32x4){0.f, 0.f, 0.f, 0.f};
            bf16x8 b0 = *(bf16x8*)&k_lds[f * 16 + l16][lhi * 8];
            bf16x8 b1 = *(bf16x8*)&k_lds[f * 16 + l16][32 + lhi * 8];
            z = mfma16(qf0, b0, z);
            z = mfma16(qf1, b1, z);
            sf[f] = z;
        }
#pragma unroll
        for (int f = 0; f < 4; ++f) {
#pragma unroll
            for (int r = 0; r < 4; ++r) {
                float sv = sf[f][r] * 0.125f;
                if (mask) {
                    int t_row = wv * 16 + lhi * 4 + r;
                    int s_loc = f * 16 + l16;
                    if (s_loc > t_row) sv = -1e30f;
                }
                sf[f][r] = sv;
            }
        }
        float mt[4];
#pragma unroll
        for (int r = 0; r < 4; ++r)
            mt[r] = fmaxf(fmaxf(sf[0][r], sf[1][r]), fmaxf(sf[2][r], sf[3][r]));
#pragma unroll
        for (int off = 1; off < 16; off <<= 1) {
#pragma unroll
            for (int r = 0; r < 4; ++r) mt[r] = fmaxf(mt[r], __shfl_xor(mt[r], off));
        }
        float fac[4];
#pragma unroll
        for (int r = 0; r < 4; ++r) {
            float mn = fmaxf(m[r], mt[r]);
            fac[r] = __expf(m[r] - mn);
            m[r] = mn;
        }
        float ladd[4] = {0.f, 0.f, 0.f, 0.f};
#pragma unroll
        for (int f = 0; f < 4; ++f) {
#pragma unroll
            for (int r = 0; r < 4; ++r) {
                float pv = __expf(sf[f][r] - m[r]);
                sf[f][r] = pv;
                ladd[r] += pv;
            }
        }
#pragma unroll
        for (int off = 1; off < 16; off <<= 1) {
#pragma unroll
            for (int r = 0; r < 4; ++r) ladd[r] += __shfl_xor(ladd[r], off);
        }
#pragma unroll
        for (int r = 0; r < 4; ++r) l[r] = l[r] * fac[r] + ladd[r];
#pragma unroll
        for (int f = 0; f < 4; ++f)
#pragma unroll
            for (int r = 0; r < 4; ++r) acc[f][r] *= fac[r];
#pragma unroll
        for (int f = 0; f < 4; ++f)
#pragma unroll
            for (int r = 0; r < 4; ++r)
                p_lds[wv * 16 + lhi * 4 + r][f * 16 + l16] = (__bf16)sf[f][r];
        bf16x8 pa0 = *(bf16x8*)&p_lds[wv * 16 + l16][lhi * 8];
        bf16x8 pa1 = *(bf16x8*)&p_lds[wv * 16 + l16][32 + lhi * 8];
#pragma unroll
        for (int f = 0; f < 4; ++f) {
            bf16x8 v0 = *(bf16x8*)&vT_lds[f * 16 + l16][lhi * 8];
            bf16x8 v1 = *(bf16x8*)&vT_lds[f * 16 + l16][32 + lhi * 8];
            acc[f] = mfma16(pa0, v0, acc[f]);
            acc[f] = mfma16(pa1, v1, acc[f]);
        }
    };

    // prefetch tile 0: K rows g+16p, V rows 4g+i (consecutive, for in-reg transpose)
    f32x4 kreg[4], vreg[4];
#pragma unroll
    for (int p = 0; p < 4; ++p)
        kreg[p] = *(const f32x4*)&ckb[(size_t)(s0 + p * 16 + g) * EE + m4];
#pragma unroll
    for (int i = 0; i < 4; ++i)
        vreg[i] = *(const f32x4*)&cvb[(size_t)(s0 + 4 * g + i) * EE + m4];

    for (int it = 0; it < 8; ++it) {
        // K: wide row writes
#pragma unroll
        for (int p = 0; p < 4; ++p) {
            bf16x4 k4 = { (__bf16)kreg[p][0], (__bf16)kreg[p][1], (__bf16)kreg[p][2], (__bf16)kreg[p][3] };
            *(bf16x4*)&k_lds[p * 16 + g][m4] = k4;
        }
        // V: 4x4 in-register transpose -> b64 writes (d-major)
#pragma unroll
        for (int j = 0; j < 4; ++j) {
            bf16x4 tv = { (__bf16)vreg[0][j], (__bf16)vreg[1][j], (__bf16)vreg[2][j], (__bf16)vreg[3][j] };
            *(bf16x4*)&vT_lds[m4 + j][4 * g] = tv;
        }
        if (it < 7) {
            int sb = s0 + (it + 1) * 64;
#pragma unroll
            for (int p = 0; p < 4; ++p)
                kreg[p] = *(const f32x4*)&ckb[(size_t)(sb + p * 16 + g) * EE + m4];
#pragma unroll
            for (int i = 0; i < 4; ++i)
                vreg[i] = *(const f32x4*)&cvb[(size_t)(sb + 4 * g + i) * EE + m4];
        }
        __syncthreads();
        compute(false);
        __syncthreads();
    }

    if (split == 7) {
#pragma unroll
        for (int p = 0; p < 2; ++p) {
            int idx = p * 256 + tid;
            int r = idx >> 3, c8 = (idx & 7) * 8;
            *(bf16x8*)&k_lds[r][c8] = *(const bf16x8*)&knew[((size_t)bh * TT + r) * DD + c8];
            bf16x8 vf = *(const bf16x8*)&vnew[((size_t)bh * TT + r) * DD + c8];
#pragma unroll
            for (int j = 0; j < 8; ++j) vT_lds[c8 + j][r] = vf[j];
        }
        __syncthreads();
        compute(true);
    }

    // store partials (bf16 O, float2 m/l)
#pragma unroll
    for (int f = 0; f < 4; ++f)
#pragma unroll
        for (int r = 0; r < 4; ++r) {
            int t = wv * 16 + lhi * 4 + r;
            int d = f * 16 + l16;
            Opart[(((size_t)split * 128 + bh) * TT + t) * DD + d] = (__bf16)acc[f][r];
        }
    if (l16 == 0) {
#pragma unroll
        for (int r = 0; r < 4; ++r) {
            int t = wv * 16 + lhi * 4 + r;
            mlpart[((size_t)split * 128 + bh) * TT + t] = make_float2(m[r], l[r]);
        }
    }
}

// ---- combine split partials -> ctx bf16 (row-major tokens x E) ----
__global__ __launch_bounds__(256) void k_combine(const __bf16* __restrict__ Opart, const float2* __restrict__ mlpart,
                                                 __bf16* __restrict__ ctxb) {
    int idx = blockIdx.x * 256 + threadIdx.x;   // B*H*T*D = 524288
    int d = idx & 63, t = (idx >> 6) & 63, bh = idx >> 12;
    float ms[NSPLIT], ls[NSPLIT];
    float mg = -1e30f;
#pragma unroll
    for (int s = 0; s < NSPLIT; ++s) {
        float2 ml = mlpart[((size_t)s * 128 + bh) * TT + t];
        ms[s] = ml.x; ls[s] = ml.y;
        mg = fmaxf(mg, ms[s]);
    }
    float den = 0.f, num = 0.f;
#pragma unroll
    for (int s = 0; s < NSPLIT; ++s) {
        float w = __expf(ms[s] - mg);
        den += ls[s] * w;
        num += (float)Opart[(((size_t)s * 128 + bh) * TT + t) * DD + d] * w;
    }
    float ctx = num / den;
    int b = bh >> 4, hh = bh & 15;
    ctxb[(size_t)(b * TT + t) * EE + hh * DD + d] = (__bf16)ctx;
}

// ---- output projection: out = ctx @ Wo (reg-prefetch, XCD-swizzled) ----
__global__ __launch_bounds__(256) void k_oproj(const __bf16* __restrict__ ctxb, const __bf16* __restrict__ WoT,
                                               float* __restrict__ out) {
    __shared__ __bf16 a_lds[64][72];
    __shared__ __bf16 b_lds[64][72];
    int xcd = blockIdx.x & 7, idx = blockIdx.x >> 3;
    int bn = xcd * 2 + (idx & 1);
    int bm = idx >> 1;
    int n0 = bn * 64, m0 = bm * 64;
    int tid = threadIdx.x;
    int wv = tid >> 6, lane = tid & 63;
    int l16 = lane & 15, lhi = lane >> 4;
    int r0 = tid >> 3, c8 = (tid & 7) * 8;
    f32x4 acc[4];
#pragma unroll
    for (int f = 0; f < 4; ++f) acc[f] = (f32x4){0.f, 0.f, 0.f, 0.f};

    bf16x8 ar0 = *(const bf16x8*)&ctxb[(size_t)(m0 + r0) * EE + c8];
    bf16x8 ar1 = *(const bf16x8*)&ctxb[(size_t)(m0 + 32 + r0) * EE + c8];
    bf16x8 br0 = *(const bf16x8*)&WoT[(size_t)(n0 + r0) * EE + c8];
    bf16x8 br1 = *(const bf16x8*)&WoT[(size_t)(n0 + 32 + r0) * EE + c8];

    for (int kt = 0; kt < 16; ++kt) {
        __syncthreads();
        *(bf16x8*)&a_lds[r0][c8] = ar0;
        *(bf16x8*)&a_lds[32 + r0][c8] = ar1;
        *(bf16x8*)&b_lds[r0][c8] = br0;
        *(bf16x8*)&b_lds[32 + r0][c8] = br1;
        if (kt < 15) {
            int ko = (kt + 1) * 64;
            ar0 = *(const bf16x8*)&ctxb[(size_t)(m0 + r0) * EE + ko + c8];
            ar1 = *(const bf16x8*)&ctxb[(size_t)(m0 + 32 + r0) * EE + ko + c8];
            br0 = *(const bf16x8*)&WoT[(size_t)(n0 + r0) * EE + ko + c8];
            br1 = *(const bf16x8*)&WoT[(size_t)(n0 + 32 + r0) * EE + ko + c8];
        }
        __syncthreads();
        bf16x8 a0 = *(bf16x8*)&a_lds[wv * 16 + l16][lhi * 8];
        bf16x8 a1 = *(bf16x8*)&a_lds[wv * 16 + l16][32 + lhi * 8];
#pragma unroll
        for (int f = 0; f < 4; ++f) {
            bf16x8 b0 = *(bf16x8*)&b_lds[f * 16 + l16][lhi * 8];
            bf16x8 b1 = *(bf16x8*)&b_lds[f * 16 + l16][32 + lhi * 8];
            acc[f] = mfma16(a0, b0, acc[f]);
            acc[f] = mfma16(a1, b1, acc[f]);
        }
    }
#pragma unroll
    for (int f = 0; f < 4; ++f)
#pragma unroll
        for (int r = 0; r < 4; ++r) {
            int row = m0 + wv * 16 + lhi * 4 + r;
            out[(size_t)row * EE + n0 + f * 16 + l16] = acc[f][r];
        }
}

extern "C" void kernel_launch(void* const* d_in, const int* in_sizes, int n_in,
                              void* d_out, int out_size, void* d_ws, size_t ws_size,
                              hipStream_t stream) {
    const float* x  = (const float*)d_in[0];
    const float* ck = (const float*)d_in[1];
    const float* cv = (const float*)d_in[2];
    const float* Wq = (const float*)d_in[3];
    const float* Wk = (const float*)d_in[4];
    const float* Wv = (const float*)d_in[5];
    const float* Wo = (const float*)d_in[6];
    const int* sp   = (const int*)d_in[7];
    float* out = (float*)d_out;

    char* p = (char*)d_ws;
    float* cs = (float*)p;              p += 2048;
    float* sn = (float*)p;              p += 2048;
    __bf16* xb = (__bf16*)p;            p += (size_t)512 * 1024 * 2;
    __bf16* WT = (__bf16*)p;            p += (size_t)4 * 1024 * 1024 * 2;
    __bf16* qws = (__bf16*)p;           p += (size_t)524288 * 2;
    __bf16* knew = (__bf16*)p;          p += (size_t)524288 * 2;
    __bf16* vnew = (__bf16*)p;          p += (size_t)524288 * 2;
    __bf16* Opart = (__bf16*)p;         p += (size_t)NSPLIT * 128 * 64 * 64 * 2;
    float2* mlpart = (float2*)p;        p += (size_t)NSPLIT * 8192 * 8;
    __bf16* ctxb = (__bf16*)p;          p += (size_t)524288 * 2;

    k_prep<<<1281, 256, 0, stream>>>(Wq, Wk, Wv, Wo, x, sp, WT, xb, cs, sn);
    k_qkv<<<384, 256, 0, stream>>>(xb, WT, cs, sn, qws, knew, vnew);
    k_attn<<<BB * HH * NSPLIT, 256, 0, stream>>>(qws, knew, vnew, ck, cv, Opart, mlpart);
    k_combine<<<2048, 256, 0, stream>>>(Opart, mlpart, ctxb);
    k_oproj<<<128, 256, 0, stream>>>(ctxb, WT + (size_t)3 * 1024 * 1024, out);
}